// Round 7
// baseline (295.789 us; speedup 1.0000x reference)
//
#include <hip/hip_runtime.h>

// Problem: N=4096, D=1024, C=1000, T=32
//   h = x @ W^T  (4096 x 2000), mu = h[:, :1000], logvar = h[:, 1000:]
//   sigma = exp(0.5*logvar)
//   eps = jax.random.normal(key(42), (32,4096,1000))  -- threefry2x32, bit-exact
//   prob = mean_t softmax(mu + sigma*eps), out0 = exp(prob), out1 = sigma

typedef __attribute__((ext_vector_type(8))) _Float16 f16x8;
typedef __attribute__((ext_vector_type(4))) float f32x4;
typedef __attribute__((ext_vector_type(2))) float f32x2;

#define NC_TOT  4096000
#define H_HALF  65536000u   // half of T*N*C = 131072000

// ---------------- fp32 -> fp16 (RNE) ----------------
__device__ __forceinline__ unsigned short f2h(float f) {
  _Float16 h = (_Float16)f;
  return __builtin_bit_cast(unsigned short, h);
}

__global__ __launch_bounds__(256) void convert_kernel(
    const float* __restrict__ x, const float* __restrict__ W,
    unsigned short* __restrict__ xh, unsigned short* __restrict__ wh) {
  int qid = blockIdx.x * 256 + threadIdx.x;
  if (qid < 1048576) {                        // x: 4096*1024/4
    float4 v = ((const float4*)x)[qid];
    ((ushort4*)xh)[qid] = make_ushort4(f2h(v.x), f2h(v.y), f2h(v.z), f2h(v.w));
  } else {
    int q = qid - 1048576;                    // padded W quad index, < 524288
    int row = q >> 8;
    ushort4 o;
    if (row < 2000) {
      float4 v = ((const float4*)W)[q];
      o = make_ushort4(f2h(v.x), f2h(v.y), f2h(v.z), f2h(v.w));
    } else {
      o = make_ushort4(0, 0, 0, 0);
    }
    ((ushort4*)wh)[q] = o;
  }
}

// ---------------- fp16 MFMA GEMM, m97 structure + XCD-aware swizzle ----------------
#define BK 32

typedef __attribute__((address_space(3))) unsigned char lds_byte;
typedef __attribute__((address_space(1))) unsigned char glb_byte;

__device__ __forceinline__ void glds16(const unsigned short* g, unsigned short* l) {
  __builtin_amdgcn_global_load_lds((const glb_byte*)g, (lds_byte*)l, 16, 0, 0);
}

__global__ __launch_bounds__(256) void gemm_kernel(
    const unsigned short* __restrict__ Ah,    // [4096][1024] fp16 bits
    const unsigned short* __restrict__ Bh,    // [2048][1024] fp16 bits, padded
    float* __restrict__ mu,                   // [4096][1000]
    float* __restrict__ sigma_out) {          // d_out + NC_TOT
  const int K = 1024;
  __shared__ unsigned short As[128 * BK];
  __shared__ unsigned short Bs[128 * BK];

  // XCD-aware swizzle: consecutive ids round-robin XCDs (id&7). Give each XCD
  // a 4-row (by) x 16-col (bx) stripe: its 64 concurrent blocks share a tiny
  // per-kk slice working set -> cross-block A/B re-reads hit the XCD L2.
  int id  = blockIdx.x;                 // 0..511
  int xcd = id & 7;
  int k9  = id >> 3;                    // 0..63
  int by  = xcd * 4 + (k9 >> 4);        // 0..31
  int bx  = k9 & 15;                    // 0..15

  int tid  = threadIdx.x;
  int w    = tid >> 6;
  int lane = tid & 63;
  int wr   = (w >> 1) * 64;
  int wc   = (w & 1) * 64;
  int lrow = lane & 15;
  int kq   = lane >> 4;

  f32x4 acc[4][4];
  for (int i = 0; i < 4; i++)
    for (int j = 0; j < 4; j++) acc[i][j] = (f32x4){0.f, 0.f, 0.f, 0.f};

  int srow = w * 16 + (lane >> 2);
  int scol = (lane & 3) * 8;
  const unsigned short* Ap = Ah + (by * 128 + srow) * K + scol;
  const unsigned short* Bp = Bh + (bx * 128 + srow) * K + scol;
  unsigned short* lA = As + w * 512;
  unsigned short* lB = Bs + w * 512;

  for (int kk = 0; kk < K; kk += BK) {
    __syncthreads();
    glds16(Ap + kk,            lA);
    glds16(Ap + kk + 64 * K,   lA + 2048);
    glds16(Bp + kk,            lB);
    glds16(Bp + kk + 64 * K,   lB + 2048);
    __syncthreads();

    f16x8 a[4], b[4];
    for (int i = 0; i < 4; i++)
      a[i] = *(const f16x8*)(As + (wr + i * 16 + lrow) * BK + kq * 8);
    for (int j = 0; j < 4; j++)
      b[j] = *(const f16x8*)(Bs + (wc + j * 16 + lrow) * BK + kq * 8);
    for (int i = 0; i < 4; i++)
      for (int j = 0; j < 4; j++)
        acc[i][j] = __builtin_amdgcn_mfma_f32_16x16x32_f16(a[i], b[j], acc[i][j], 0, 0, 0);
  }

  // C/D layout: col = lane&15 (N), row = (lane>>4)*4 + reg (M)
  int orow0 = by * 128 + wr + (lane >> 4) * 4;
  int ocol0 = bx * 128 + wc + (lane & 15);
  for (int i = 0; i < 4; i++) {
    for (int j = 0; j < 4; j++) {
      int c = ocol0 + j * 16;
      for (int v = 0; v < 4; v++) {
        int r = orow0 + i * 16 + v;
        float val = acc[i][j][v];
        if (c < 1000)       mu[r * 1000 + c] = val;
        else if (c < 2000)  sigma_out[r * 1000 + (c - 1000)] = __expf(0.5f * val);
      }
    }
  }
}

// ---------------- threefry2x32 x2, key = (0,42), source-interleaved ----------------
#define ROTL(x, r) __builtin_amdgcn_alignbit((x), (x), 32 - (r))

__device__ __forceinline__ void threefry2(unsigned a, unsigned b,
                                          unsigned& oa0, unsigned& oa1,
                                          unsigned& ob0, unsigned& ob1) {
  const unsigned ks1 = 42u;
  const unsigned ks2 = 0x1BD11BDAu ^ 42u;
  unsigned xa0 = a, xa1 = a + H_HALF + ks1;   // x1 = ctr_hi; x1 += ks1 (folded)
  unsigned xb0 = b, xb1 = b + H_HALF + ks1;
#define TF2(r) { xa0 += xa1; xb0 += xb1; \
                 xa1 = ROTL(xa1, r) ^ xa0; xb1 = ROTL(xb1, r) ^ xb0; }
  TF2(13) TF2(15) TF2(26) TF2(6)
  xa0 += ks1; xa1 += ks2 + 1u;  xb0 += ks1; xb1 += ks2 + 1u;
  TF2(17) TF2(29) TF2(16) TF2(24)
  xa0 += ks2; xa1 += 2u;        xb0 += ks2; xb1 += 2u;
  TF2(13) TF2(15) TF2(26) TF2(6)
  xa1 += ks1 + 3u;              xb1 += ks1 + 3u;
  TF2(17) TF2(29) TF2(16) TF2(24)
  xa0 += ks1; xa1 += ks2 + 4u;  xb0 += ks1; xb1 += ks2 + 4u;
  TF2(13) TF2(15) TF2(26) TF2(6)
  xa0 += ks2; xa1 += 5u;        xb0 += ks2; xb1 += 5u;
#undef TF2
  oa0 = xa0; oa1 = xa1; ob0 = xb0; ob1 = xb1;
}

__device__ __forceinline__ float erfinv_big(float x, float w) {
  float v = __fsqrt_rn(w) - 3.0f;
  float p = -0.000200214257f;
  p = fmaf(p, v, 0.000100950558f);
  p = fmaf(p, v, 0.00134934322f);
  p = fmaf(p, v, -0.00367342844f);
  p = fmaf(p, v, 0.00573950773f);
  p = fmaf(p, v, -0.0076224613f);
  p = fmaf(p, v, 0.00943887047f);
  p = fmaf(p, v, 1.00167406f);
  p = fmaf(p, v, 2.83297682f);
  return 1.41421356f * (p * x);
}

__device__ __forceinline__ f32x4 splat4(float c) { return (f32x4){c, c, c, c}; }

__device__ __forceinline__ f32x4 bits_to_u4(unsigned b0, unsigned b1,
                                            unsigned b2, unsigned b3) {
  f32x4 f;
  f.x = __builtin_bit_cast(float, (b0 >> 9) | 0x3f800000u);
  f.y = __builtin_bit_cast(float, (b1 >> 9) | 0x3f800000u);
  f.z = __builtin_bit_cast(float, (b2 >> 9) | 0x3f800000u);
  f.w = __builtin_bit_cast(float, (b3 >> 9) | 0x3f800000u);
  f = f - splat4(1.0f);
  return __builtin_elementwise_fma(f, splat4(2.0f), splat4(-0.99999994f));
}

// Central-path polynomial always (packed); the rare tail (P≈0.34%/sample) is
// guarded by __ballot so it is a wave-uniform scalar branch, NOT if-converted
// into every element's instruction stream (r6 post-mortem: the always-executed
// dual polynomial was ~17 slots/element of pure waste).
__device__ __forceinline__ f32x4 normal4(f32x4 x) {
  f32x4 t = __builtin_elementwise_fma(-x, x, splat4(1.0f));
  f32x4 lg;
  lg.x = __builtin_amdgcn_logf(t.x);
  lg.y = __builtin_amdgcn_logf(t.y);
  lg.z = __builtin_amdgcn_logf(t.z);
  lg.w = __builtin_amdgcn_logf(t.w);
  f32x4 w = lg * splat4(-0.69314718f);
  f32x4 v = w - splat4(2.5f);
  f32x4 p = splat4(2.81022636e-08f);
  p = __builtin_elementwise_fma(p, v, splat4(3.43273939e-07f));
  p = __builtin_elementwise_fma(p, v, splat4(-3.5233877e-06f));
  p = __builtin_elementwise_fma(p, v, splat4(-4.39150654e-06f));
  p = __builtin_elementwise_fma(p, v, splat4(0.00021858087f));
  p = __builtin_elementwise_fma(p, v, splat4(-0.00125372503f));
  p = __builtin_elementwise_fma(p, v, splat4(-0.00417768164f));
  p = __builtin_elementwise_fma(p, v, splat4(0.246640727f));
  p = __builtin_elementwise_fma(p, v, splat4(1.50140941f));
  f32x4 r = (p * x) * splat4(1.41421356f);
  if (__ballot(w.x >= 5.0f)) { if (w.x >= 5.0f) r.x = erfinv_big(x.x, w.x); }
  if (__ballot(w.y >= 5.0f)) { if (w.y >= 5.0f) r.y = erfinv_big(x.y, w.y); }
  if (__ballot(w.z >= 5.0f)) { if (w.z >= 5.0f) r.z = erfinv_big(x.z, w.z); }
  if (__ballot(w.w >= 5.0f)) { if (w.w >= 5.0f) r.w = erfinv_big(x.w, w.w); }
  return r;
}

// ---------------- sampling ----------------
// 256 thr = 4 waves per row n, wave w owns t-pairs 4w..4w+3, no in-loop
// barriers. mu/sigma in LDS. Padding classes (c>=1000) get mu=-1e30, sigma=0
// -> exp(logit)=0 naturally, no masking instructions in the hot loop.
__global__ __launch_bounds__(256) void sample_kernel(
    const float* __restrict__ mu,      // ws
    const float* __restrict__ sigma,   // d_out + NC
    float* __restrict__ out0) {        // d_out
  int n    = blockIdx.x;
  int tid  = threadIdx.x;
  int lane = tid & 63, w = tid >> 6;
  __shared__ float2 msb[1024];         // (mu, sigma), 8 KB
  __shared__ float  pbuf[4][1024];     // per-wave prob partials, 16 KB

  int cb = n * 1000;
#pragma unroll
  for (int k = 0; k < 4; k++) {
    int c = tid + k * 256;
    float2 v;
    if (c < 1000) { v.x = mu[cb + c]; v.y = sigma[cb + c]; }
    else          { v.x = -1e30f;     v.y = 0.f; }          // exp -> 0
    msb[c] = v;
  }
  __syncthreads();

  float prob[16];
#pragma unroll
  for (int j = 0; j < 16; j++) prob[j] = 0.f;

  f32x4 e4[8];
#pragma unroll 1
  for (int it = 0; it < 4; it++) {
    int t = w * 4 + it;
    unsigned ib = (unsigned)(t * 4096000 + cb) + (unsigned)lane;
    f32x4 s4 = splat4(0.f);
#pragma unroll
    for (int jj = 0; jj < 8; jj++) {
      int j0 = jj * 2, j1 = jj * 2 + 1;
      float2 ms0 = msb[j0 * 64 + lane];          // stride-2 banks: free 2-way
      float2 ms1 = msb[j1 * 64 + lane];
      unsigned i0 = ib + (unsigned)(j0 * 64);
      unsigned o00, o01, o10, o11;
      threefry2(i0, i0 + 64u, o00, o01, o10, o11);
      f32x4 eps = normal4(bits_to_u4(o00, o01, o10, o11));
      f32x4 mu4 = (f32x4){ms0.x, ms0.x, ms1.x, ms1.x};
      f32x4 sg4 = (f32x4){ms0.y, ms0.y, ms1.y, ms1.y};
      f32x4 lgt = __builtin_elementwise_fma(sg4, eps, mu4);
      f32x4 ev;
      ev.x = __expf(lgt.x);                      // chunk j0, sample t
      ev.y = __expf(lgt.y);                      // chunk j0, sample t+16
      ev.z = __expf(lgt.z);                      // chunk j1, sample t
      ev.w = __expf(lgt.w);                      // chunk j1, sample t+16
      e4[jj] = ev;
      s4 = s4 + ev;
    }
    float sA = s4.x + s4.z, sB = s4.y + s4.w;
#pragma unroll
    for (int m = 1; m < 64; m <<= 1) {
      sA += __shfl_xor(sA, m, 64);
      sB += __shfl_xor(sB, m, 64);
    }
    float rA = 1.0f / sA, rB = 1.0f / sB;
#pragma unroll
    for (int jj = 0; jj < 8; jj++) {
      prob[jj * 2]     = fmaf(e4[jj].x, rA, fmaf(e4[jj].y, rB, prob[jj * 2]));
      prob[jj * 2 + 1] = fmaf(e4[jj].z, rA, fmaf(e4[jj].w, rB, prob[jj * 2 + 1]));
    }
  }

#pragma unroll
  for (int j = 0; j < 16; j++)
    pbuf[w][j * 64 + lane] = prob[j];
  __syncthreads();
#pragma unroll
  for (int k = 0; k < 4; k++) {
    int c = tid + k * 256;
    if (c < 1000) {
      float sm = (pbuf[0][c] + pbuf[1][c]) + (pbuf[2][c] + pbuf[3][c]);
      out0[cb + c] = __expf(sm * 0.03125f);
    }
  }
}

// ---------------- launch ----------------
extern "C" void kernel_launch(void* const* d_in, const int* in_sizes, int n_in,
                              void* d_out, int out_size, void* d_ws, size_t ws_size,
                              hipStream_t stream) {
  const float* x = (const float*)d_in[0];   // 4096*1024
  const float* W = (const float*)d_in[1];   // 2000*1024
  float* out = (float*)d_out;               // [mu_out | sigma], each 4096000

  unsigned short* xh = (unsigned short*)d_ws;                        //  8,388,608 B
  unsigned short* wh = (unsigned short*)((char*)d_ws + 8388608);     //  4,194,304 B
  float*          mu = (float*)((char*)d_ws + 12582912);             // 16,384,000 B
  float* sigma = out + NC_TOT;

  convert_kernel<<<6144, 256, 0, stream>>>(x, W, xh, wh);
  gemm_kernel<<<512, 256, 0, stream>>>(xh, wh, mu, sigma);
  sample_kernel<<<4096, 256, 0, stream>>>(mu, sigma, out);
}

// Round 8
// 289.638 us; speedup vs baseline: 1.0212x; 1.0212x over previous
//
#include <hip/hip_runtime.h>

// Problem: N=4096, D=1024, C=1000, T=32
//   h = x @ W^T  (4096 x 2000), mu = h[:, :1000], logvar = h[:, 1000:]
//   sigma = exp(0.5*logvar)
//   eps = jax.random.normal(key(42), (32,4096,1000))  -- threefry2x32, bit-exact
//   prob = mean_t softmax(mu + sigma*eps), out0 = exp(prob), out1 = sigma

typedef __attribute__((ext_vector_type(8))) _Float16 f16x8;
typedef __attribute__((ext_vector_type(4))) float f32x4;
typedef __attribute__((ext_vector_type(2))) float f32x2;

#define NC_TOT  4096000
#define H_HALF  65536000u   // half of T*N*C = 131072000

// ---------------- fp32 -> fp16 (RNE) ----------------
__device__ __forceinline__ unsigned short f2h(float f) {
  _Float16 h = (_Float16)f;
  return __builtin_bit_cast(unsigned short, h);
}

__global__ __launch_bounds__(256) void convert_kernel(
    const float* __restrict__ x, const float* __restrict__ W,
    unsigned short* __restrict__ xh, unsigned short* __restrict__ wh) {
  int qid = blockIdx.x * 256 + threadIdx.x;
  if (qid < 1048576) {                        // x: 4096*1024/4
    float4 v = ((const float4*)x)[qid];
    ((ushort4*)xh)[qid] = make_ushort4(f2h(v.x), f2h(v.y), f2h(v.z), f2h(v.w));
  } else {
    int q = qid - 1048576;                    // padded W quad index, < 524288
    int row = q >> 8;
    ushort4 o;
    if (row < 2000) {
      float4 v = ((const float4*)W)[q];
      o = make_ushort4(f2h(v.x), f2h(v.y), f2h(v.z), f2h(v.w));
    } else {
      o = make_ushort4(0, 0, 0, 0);
    }
    ((ushort4*)wh)[q] = o;
  }
}

// ---------------- fp16 MFMA GEMM: 128x64 tiles, 1024 blocks (4/CU) ----------------
// r7 post-mortem: 512 blocks = 2 blocks/CU left the barrier drain uncovered.
// 128x64 doubles the grid; each wave does 64x32 (acc[4][2], 8 MFMA/K-step).
#define BK 32

typedef __attribute__((address_space(3))) unsigned char lds_byte;
typedef __attribute__((address_space(1))) unsigned char glb_byte;

__device__ __forceinline__ void glds16(const unsigned short* g, unsigned short* l) {
  __builtin_amdgcn_global_load_lds((const glb_byte*)g, (lds_byte*)l, 16, 0, 0);
}

__global__ __launch_bounds__(256) void gemm_kernel(
    const unsigned short* __restrict__ Ah,    // [4096][1024] fp16 bits
    const unsigned short* __restrict__ Bh,    // [2048][1024] fp16 bits, padded
    float* __restrict__ mu,                   // [4096][1000]
    float* __restrict__ sigma_out) {          // d_out + NC_TOT
  const int K = 1024;
  __shared__ unsigned short As[128 * BK];     // 8 KB
  __shared__ unsigned short Bs[64 * BK];      // 4 KB

  // XCD swizzle: id&7 -> XCD; each XCD gets a 4(by) x 32(bx) stripe.
  int id  = blockIdx.x;                 // 0..1023
  int xcd = id & 7;
  int q9  = id >> 3;                    // 0..127
  int by  = xcd * 4 + (q9 >> 5);        // 0..31
  int bx  = q9 & 31;                    // 0..31

  int tid  = threadIdx.x;
  int w    = tid >> 6;
  int lane = tid & 63;
  int wr   = (w >> 1) * 64;             // wave row offset (0/64)
  int wc   = (w & 1) * 32;              // wave col offset (0/32)
  int lrow = lane & 15;
  int kq   = lane >> 4;

  f32x4 acc[4][2];
  for (int i = 0; i < 4; i++)
    for (int j = 0; j < 2; j++) acc[i][j] = (f32x4){0.f, 0.f, 0.f, 0.f};

  // staging: wave w stages 16 rows per glds16 call; LDS addr = w*512 + lane*8
  int srow = w * 16 + (lane >> 2);
  int scol = (lane & 3) * 8;
  const unsigned short* Ap = Ah + (by * 128 + srow) * K + scol;
  const unsigned short* Bp = Bh + (bx * 64  + srow) * K + scol;   // srow < 64
  unsigned short* lA = As + w * 512;
  unsigned short* lB = Bs + w * 512;

  for (int kk = 0; kk < K; kk += BK) {
    __syncthreads();
    glds16(Ap + kk,          lA);             // A rows 0..63
    glds16(Ap + kk + 64 * K, lA + 2048);      // A rows 64..127
    glds16(Bp + kk,          lB);             // B rows 0..63
    __syncthreads();

    f16x8 a[4], b[2];
    for (int i = 0; i < 4; i++)
      a[i] = *(const f16x8*)(As + (wr + i * 16 + lrow) * BK + kq * 8);
    for (int j = 0; j < 2; j++)
      b[j] = *(const f16x8*)(Bs + (wc + j * 16 + lrow) * BK + kq * 8);
    for (int i = 0; i < 4; i++)
      for (int j = 0; j < 2; j++)
        acc[i][j] = __builtin_amdgcn_mfma_f32_16x16x32_f16(a[i], b[j], acc[i][j], 0, 0, 0);
  }

  // C/D layout: col = lane&15 (N), row = (lane>>4)*4 + reg (M)
  int orow0 = by * 128 + wr + (lane >> 4) * 4;
  int ocol0 = bx * 64 + wc + (lane & 15);
  for (int i = 0; i < 4; i++) {
    for (int j = 0; j < 2; j++) {
      int c = ocol0 + j * 16;
      for (int v = 0; v < 4; v++) {
        int r = orow0 + i * 16 + v;
        float val = acc[i][j][v];
        if (c < 1000)       mu[r * 1000 + c] = val;
        else if (c < 2000)  sigma_out[r * 1000 + (c - 1000)] = __expf(0.5f * val);
      }
    }
  }
}

// ---------------- threefry2x32, key = (0, 42) ----------------
__device__ __forceinline__ void threefry(unsigned x0, unsigned x1,
                                         unsigned& o0, unsigned& o1) {
  const unsigned ks1 = 42u;
  const unsigned ks2 = 0x1BD11BDAu ^ 42u;
#define TF_RND(r) { x0 += x1; x1 = (x1 << (r)) | (x1 >> (32 - (r))); x1 ^= x0; }
  x1 += ks1;
  TF_RND(13) TF_RND(15) TF_RND(26) TF_RND(6)
  x0 += ks1;  x1 += ks2 + 1u;
  TF_RND(17) TF_RND(29) TF_RND(16) TF_RND(24)
  x0 += ks2;  x1 += 2u;
  TF_RND(13) TF_RND(15) TF_RND(26) TF_RND(6)
  x1 += ks1 + 3u;
  TF_RND(17) TF_RND(29) TF_RND(16) TF_RND(24)
  x0 += ks1;  x1 += ks2 + 4u;
  TF_RND(13) TF_RND(15) TF_RND(26) TF_RND(6)
  x0 += ks2;  x1 += 5u;
#undef TF_RND
  o0 = x0; o1 = x1;
}

__device__ __forceinline__ float erfinv_big(float x, float w) {
  float v = __fsqrt_rn(w) - 3.0f;
  float p = -0.000200214257f;
  p = fmaf(p, v, 0.000100950558f);
  p = fmaf(p, v, 0.00134934322f);
  p = fmaf(p, v, -0.00367342844f);
  p = fmaf(p, v, 0.00573950773f);
  p = fmaf(p, v, -0.0076224613f);
  p = fmaf(p, v, 0.00943887047f);
  p = fmaf(p, v, 1.00167406f);
  p = fmaf(p, v, 2.83297682f);
  return 1.41421356f * (p * x);
}

__device__ __forceinline__ f32x2 splat2(float c) { return (f32x2){c, c}; }

__device__ __forceinline__ f32x2 normal2(f32x2 x) {
  f32x2 t = __builtin_elementwise_fma(-x, x, splat2(1.0f));
  f32x2 lg;
  lg.x = __builtin_amdgcn_logf(t.x);
  lg.y = __builtin_amdgcn_logf(t.y);
  f32x2 w = lg * splat2(-0.69314718f);
  f32x2 v = w - splat2(2.5f);
  f32x2 p = splat2(2.81022636e-08f);
  p = __builtin_elementwise_fma(p, v, splat2(3.43273939e-07f));
  p = __builtin_elementwise_fma(p, v, splat2(-3.5233877e-06f));
  p = __builtin_elementwise_fma(p, v, splat2(-4.39150654e-06f));
  p = __builtin_elementwise_fma(p, v, splat2(0.00021858087f));
  p = __builtin_elementwise_fma(p, v, splat2(-0.00125372503f));
  p = __builtin_elementwise_fma(p, v, splat2(-0.00417768164f));
  p = __builtin_elementwise_fma(p, v, splat2(0.246640727f));
  p = __builtin_elementwise_fma(p, v, splat2(1.50140941f));
  f32x2 r = (p * x) * splat2(1.41421356f);
  if (w.x >= 5.0f) r.x = erfinv_big(x.x, w.x);   // rare (~0.34%/sample)
  if (w.y >= 5.0f) r.y = erfinv_big(x.y, w.y);
  return r;
}

__device__ __forceinline__ f32x2 bits_to_u2(unsigned b0, unsigned b1) {
  f32x2 f;
  f.x = __builtin_bit_cast(float, (b0 >> 9) | 0x3f800000u);
  f.y = __builtin_bit_cast(float, (b1 >> 9) | 0x3f800000u);
  f = f - splat2(1.0f);
  return __builtin_elementwise_fma(f, splat2(2.0f), splat2(-0.99999994f));
}

// ---------------- sampling (exact round-2 code: best measured, 209.0 µs) ----------------
// 1 block per row n; wave w owns t-pairs 4w..4w+3; all 1000 c in 16 reg chunks.
__global__ __launch_bounds__(256) void sample_kernel(
    const float* __restrict__ mu,      // ws
    const float* __restrict__ sigma,   // d_out + NC
    float* __restrict__ out0) {        // d_out
  int n    = blockIdx.x;
  int tid  = threadIdx.x;
  int lane = tid & 63, w = tid >> 6;
  __shared__ float pbuf[4][1024];

  int cb = n * 1000;
  float muv[16], sgv[16], prob[16];
#pragma unroll
  for (int j = 0; j < 16; j++) {
    int c = j * 64 + lane;
    bool val = (c < 1000);
    muv[j] = val ? mu[cb + c]    : 0.f;
    sgv[j] = val ? sigma[cb + c] : 0.f;
    prob[j] = 0.f;
  }

  f32x2 e[16];
#pragma unroll 1
  for (int it = 0; it < 4; it++) {
    int t = w * 4 + it;
    unsigned ib = (unsigned)(t * 4096000 + cb) + (unsigned)lane;
    f32x2 s = splat2(0.f);
#pragma unroll
    for (int j = 0; j < 16; j++) {
      unsigned i0 = ib + (unsigned)(j * 64);
      unsigned o0, o1;
      threefry(i0, i0 + H_HALF, o0, o1);
      f32x2 eps = normal2(bits_to_u2(o0, o1));
      f32x2 lg = __builtin_elementwise_fma(splat2(sgv[j]), eps, splat2(muv[j]));
      f32x2 ev;
      ev.x = __expf(lg.x);                       // sample t
      ev.y = __expf(lg.y);                       // sample t+16
      if (j == 15) {                             // classes >= 1000 are padding
        ev.x = (lane < 40) ? ev.x : 0.f;
        ev.y = (lane < 40) ? ev.y : 0.f;
      }
      e[j] = ev;
      s = s + ev;
    }
#pragma unroll
    for (int m = 1; m < 64; m <<= 1) {
      s.x += __shfl_xor(s.x, m, 64);
      s.y += __shfl_xor(s.y, m, 64);
    }
    float rA = 1.0f / s.x, rB = 1.0f / s.y;
#pragma unroll
    for (int j = 0; j < 16; j++)
      prob[j] = fmaf(e[j].x, rA, fmaf(e[j].y, rB, prob[j]));
  }

#pragma unroll
  for (int j = 0; j < 16; j++)
    pbuf[w][j * 64 + lane] = prob[j];
  __syncthreads();
#pragma unroll
  for (int k = 0; k < 4; k++) {
    int c = tid + k * 256;
    if (c < 1000) {
      float sm = pbuf[0][c] + pbuf[1][c] + pbuf[2][c] + pbuf[3][c];
      out0[cb + c] = __expf(sm * 0.03125f);
    }
  }
}

// ---------------- launch ----------------
extern "C" void kernel_launch(void* const* d_in, const int* in_sizes, int n_in,
                              void* d_out, int out_size, void* d_ws, size_t ws_size,
                              hipStream_t stream) {
  const float* x = (const float*)d_in[0];   // 4096*1024
  const float* W = (const float*)d_in[1];   // 2000*1024
  float* out = (float*)d_out;               // [mu_out | sigma], each 4096000

  unsigned short* xh = (unsigned short*)d_ws;                        //  8,388,608 B
  unsigned short* wh = (unsigned short*)((char*)d_ws + 8388608);     //  4,194,304 B
  float*          mu = (float*)((char*)d_ws + 12582912);             // 16,384,000 B
  float* sigma = out + NC_TOT;

  convert_kernel<<<6144, 256, 0, stream>>>(x, W, xh, wh);
  gemm_kernel<<<1024, 256, 0, stream>>>(xh, wh, mu, sigma);
  sample_kernel<<<4096, 256, 0, stream>>>(mu, sigma, out);
}